// Round 3
// baseline (257.115 us; speedup 1.0000x reference)
//
#include <hip/hip_runtime.h>
#include <math.h>

// LowRankChristoffel: out = clip((((v@U)^2) @ W^T) * (1+sigmoid(x@Vw^T)), +-5)
// B=4, S=4096, D=2048, R=16, fp32. HBM floor: 384 MiB -> ~64 us.
//
// R2/R3 changes vs R1 (which was LDS-throughput/latency bound at 163 us):
//  - phase 1: 4 rows/wave -> each u4 LDS read feeds 16 FMAs (LDS traffic /4)
//  - phase 2: W held in registers (thread owns d=2t,2t+1) -> no W LDS traffic,
//    no restage, one barrier deleted. sq read via wave-uniform LDS broadcast.
//  - nontemporal stores for the streamed output (ext_vector type, not HIP float2).

constexpr int D_DIM   = 2048;
constexpr int R_DIM   = 16;
constexpr int ROWS    = 64;       // rows per block
constexpr int THREADS = 1024;     // 16 waves
constexpr int WAVES   = THREADS / 64;
constexpr int RPW     = ROWS / WAVES;   // 4 rows per wave

typedef float f32x2 __attribute__((ext_vector_type(2)));

// dynamic LDS (floats): U^T [R][D] + Vw [D] + sq [ROWS][R] + fac [ROWS]
constexpr int SMEM_FLOATS = R_DIM * D_DIM + D_DIM + ROWS * R_DIM + ROWS;
constexpr size_t SMEM_BYTES = (size_t)SMEM_FLOATS * sizeof(float);

__device__ __forceinline__ float clamp5(float v) {
    return fminf(fmaxf(v, -5.0f), 5.0f);
}
__device__ __forceinline__ float dot4(float4 a, float4 b) {
    return a.x * b.x + a.y * b.y + a.z * b.z + a.w * b.w;
}

extern "C" __global__ void __launch_bounds__(THREADS, 4)
lrc_kernel(const float* __restrict__ v, const float* __restrict__ x,
           const float* __restrict__ U, const float* __restrict__ W,
           const float* __restrict__ Vw, float* __restrict__ out, int nrows)
{
    extern __shared__ float smem[];
    float* u_lds   = smem;                       // [R_DIM][D_DIM] (U transposed)
    float* vw_lds  = u_lds + R_DIM * D_DIM;      // [D_DIM]
    float* sq_lds  = vw_lds + D_DIM;             // [ROWS][R_DIM]
    float* fac_lds = sq_lds + ROWS * R_DIM;      // [ROWS]

    const int tid  = threadIdx.x;
    const int lane = tid & 63;
    const int wave = tid >> 6;          // 0..15
    const int row0 = blockIdx.x * ROWS;

    // ---- stage Vw (coalesced float4) ----
    for (int i = tid; i < D_DIM / 4; i += THREADS)
        reinterpret_cast<float4*>(vw_lds)[i] = reinterpret_cast<const float4*>(Vw)[i];

    // ---- stage U transposed: thread handles d = 2*tid, 2*tid+1 ----
    {
        const int dd = tid * 2;
        float u0[R_DIM], u1[R_DIM];
        const float4* p0 = reinterpret_cast<const float4*>(U + (size_t)dd * R_DIM);
        const float4* p1 = reinterpret_cast<const float4*>(U + (size_t)(dd + 1) * R_DIM);
        #pragma unroll
        for (int c = 0; c < 4; ++c) {
            *reinterpret_cast<float4*>(&u0[c * 4]) = p0[c];
            *reinterpret_cast<float4*>(&u1[c * 4]) = p1[c];
        }
        #pragma unroll
        for (int r = 0; r < R_DIM; ++r)
            *reinterpret_cast<float2*>(&u_lds[r * D_DIM + dd]) = make_float2(u0[r], u1[r]);
    }
    __syncthreads();

    // ---- phase 1: each wave computes proj^2 + modulation for 4 rows ----
    {
        const int rl0 = wave * RPW;               // local rows rl0..rl0+3
        const float* vb = v + (size_t)(row0 + rl0) * D_DIM;
        const float* xb = x + (size_t)(row0 + rl0) * D_DIM;

        float pp[RPW][R_DIM];
        float xv[RPW];
        #pragma unroll
        for (int k = 0; k < RPW; ++k) {
            xv[k] = 0.0f;
            #pragma unroll
            for (int r = 0; r < R_DIM; ++r) pp[k][r] = 0.0f;
        }

        #pragma unroll 2
        for (int i = 0; i < D_DIM / 256; ++i) {    // 8 iters, 256 floats/wave/iter
            const int d0 = i * 256 + lane * 4;
            float4 v4[RPW], x4[RPW];
            #pragma unroll
            for (int k = 0; k < RPW; ++k) {
                v4[k] = *reinterpret_cast<const float4*>(vb + (size_t)k * D_DIM + d0);
                x4[k] = *reinterpret_cast<const float4*>(xb + (size_t)k * D_DIM + d0);
            }
            const float4 vw4 = *reinterpret_cast<const float4*>(vw_lds + d0);
            #pragma unroll
            for (int k = 0; k < RPW; ++k) xv[k] += dot4(x4[k], vw4);
            #pragma unroll
            for (int r = 0; r < R_DIM; ++r) {
                const float4 u4 = *reinterpret_cast<const float4*>(u_lds + r * D_DIM + d0);
                #pragma unroll
                for (int k = 0; k < RPW; ++k) pp[k][r] += dot4(v4[k], u4);
            }
        }

        // butterfly reduce across the 64-lane wave
        #pragma unroll
        for (int s = 32; s >= 1; s >>= 1) {
            #pragma unroll
            for (int k = 0; k < RPW; ++k) {
                xv[k] += __shfl_xor(xv[k], s, 64);
                #pragma unroll
                for (int r = 0; r < R_DIM; ++r) pp[k][r] += __shfl_xor(pp[k][r], s, 64);
            }
        }
        if (lane == 0) {
            #pragma unroll
            for (int k = 0; k < RPW; ++k) {
                const int rl = rl0 + k;
                if (row0 + rl < nrows) {
                    #pragma unroll
                    for (int r = 0; r < R_DIM; ++r)
                        sq_lds[rl * R_DIM + r] = pp[k][r] * pp[k][r];
                    fac_lds[rl] = 1.0f + 1.0f / (1.0f + __expf(-xv[k]));
                }
            }
        }
    }
    __syncthreads();

    // ---- phase 2: thread owns d = 2*tid, 2*tid+1; W in registers ----
    {
        const int dd = tid * 2;
        float w0[R_DIM], w1[R_DIM];
        const float4* p0 = reinterpret_cast<const float4*>(W + (size_t)dd * R_DIM);
        const float4* p1 = reinterpret_cast<const float4*>(W + (size_t)(dd + 1) * R_DIM);
        #pragma unroll
        for (int c = 0; c < 4; ++c) {
            *reinterpret_cast<float4*>(&w0[c * 4]) = p0[c];
            *reinterpret_cast<float4*>(&w1[c * 4]) = p1[c];
        }

        for (int rl = 0; rl < ROWS; ++rl) {
            if (row0 + rl >= nrows) break;
            float sqv[R_DIM];
            #pragma unroll
            for (int c = 0; c < 4; ++c)
                *reinterpret_cast<float4*>(&sqv[c * 4]) =
                    *reinterpret_cast<const float4*>(sq_lds + rl * R_DIM + c * 4);
            const float fac = fac_lds[rl];
            float o0 = 0.0f, o1 = 0.0f;
            #pragma unroll
            for (int r = 0; r < R_DIM; ++r) {
                o0 += sqv[r] * w0[r];
                o1 += sqv[r] * w1[r];
            }
            f32x2 o;
            o.x = clamp5(o0 * fac);
            o.y = clamp5(o1 * fac);
            __builtin_nontemporal_store(o,
                reinterpret_cast<f32x2*>(out + (size_t)(row0 + rl) * D_DIM + dd));
        }
    }
}

extern "C" void kernel_launch(void* const* d_in, const int* in_sizes, int n_in,
                              void* d_out, int out_size, void* d_ws, size_t ws_size,
                              hipStream_t stream) {
    const float* v  = (const float*)d_in[0];
    const float* x  = (const float*)d_in[1];
    const float* U  = (const float*)d_in[2];
    const float* W  = (const float*)d_in[3];
    const float* Vw = (const float*)d_in[4];
    float* out = (float*)d_out;

    const int nrows = in_sizes[0] / D_DIM;        // B*S = 16384
    const int grid  = (nrows + ROWS - 1) / ROWS;  // 256

    (void)hipFuncSetAttribute((const void*)lrc_kernel,
                              hipFuncAttributeMaxDynamicSharedMemorySize,
                              (int)SMEM_BYTES);
    lrc_kernel<<<grid, THREADS, SMEM_BYTES, stream>>>(v, x, U, W, Vw, out, nrows);
}

// Round 4
// 84.523 us; speedup vs baseline: 3.0420x; 3.0420x over previous
//
#include <hip/hip_runtime.h>
#include <math.h>

// LowRankChristoffel: out = clip((((v@U)^2) @ W^T) * (1+sigmoid(x@Vw^T)), +-5)
// B=4, S=4096, D=2048, R=16, fp32. HBM floor: 384 MiB -> ~64 us.
//
// R4: fix the spill problem found in R1/R3 counters (WRITE_SIZE 2.4-4.9x ideal
// = scratch traffic; compiler capped VGPRs at 64 targeting 8 waves/EU that the
// 128 KiB LDS footprint can never reach).
//  - amdgpu_waves_per_eu(4,4): pin occupancy target to the LDS-imposed
//    1 block/CU -> allocator gets the full 128-VGPR budget.
//  - phase 1 at 2 rows/batch (pp[2][16] = 32 accs, ~80 live regs, no spill).
//  - phase 2 keeps W in registers (thread owns d=2t,2t+1), nt stores.

constexpr int D_DIM   = 2048;
constexpr int R_DIM   = 16;
constexpr int ROWS    = 64;       // rows per block
constexpr int THREADS = 1024;     // 16 waves
constexpr int WAVES   = THREADS / 64;
constexpr int RB      = 2;        // rows per batch in phase 1

typedef float f32x2 __attribute__((ext_vector_type(2)));

// dynamic LDS (floats): U^T [R][D] + Vw [D] + sq [ROWS][R] + fac [ROWS]
constexpr int SMEM_FLOATS = R_DIM * D_DIM + D_DIM + ROWS * R_DIM + ROWS;
constexpr size_t SMEM_BYTES = (size_t)SMEM_FLOATS * sizeof(float);

__device__ __forceinline__ float clamp5(float v) {
    return fminf(fmaxf(v, -5.0f), 5.0f);
}
__device__ __forceinline__ float dot4(float4 a, float4 b) {
    return a.x * b.x + a.y * b.y + a.z * b.z + a.w * b.w;
}

extern "C" __global__ void __launch_bounds__(THREADS)
__attribute__((amdgpu_waves_per_eu(4, 4)))
lrc_kernel(const float* __restrict__ v, const float* __restrict__ x,
           const float* __restrict__ U, const float* __restrict__ W,
           const float* __restrict__ Vw, float* __restrict__ out, int nrows)
{
    extern __shared__ float smem[];
    float* u_lds   = smem;                       // [R_DIM][D_DIM] (U transposed)
    float* vw_lds  = u_lds + R_DIM * D_DIM;      // [D_DIM]
    float* sq_lds  = vw_lds + D_DIM;             // [ROWS][R_DIM]
    float* fac_lds = sq_lds + ROWS * R_DIM;      // [ROWS]

    const int tid  = threadIdx.x;
    const int lane = tid & 63;
    const int wave = tid >> 6;          // 0..15
    const int row0 = blockIdx.x * ROWS;

    // ---- stage Vw (coalesced float4) ----
    for (int i = tid; i < D_DIM / 4; i += THREADS)
        reinterpret_cast<float4*>(vw_lds)[i] = reinterpret_cast<const float4*>(Vw)[i];

    // ---- stage U transposed: thread handles d = 2*tid, 2*tid+1 ----
    {
        const int dd = tid * 2;
        float u0[R_DIM], u1[R_DIM];
        const float4* p0 = reinterpret_cast<const float4*>(U + (size_t)dd * R_DIM);
        const float4* p1 = reinterpret_cast<const float4*>(U + (size_t)(dd + 1) * R_DIM);
        #pragma unroll
        for (int c = 0; c < 4; ++c) {
            *reinterpret_cast<float4*>(&u0[c * 4]) = p0[c];
            *reinterpret_cast<float4*>(&u1[c * 4]) = p1[c];
        }
        #pragma unroll
        for (int r = 0; r < R_DIM; ++r)
            *reinterpret_cast<float2*>(&u_lds[r * D_DIM + dd]) = make_float2(u0[r], u1[r]);
    }
    __syncthreads();

    // ---- phase 1: each wave: 4 rows as 2 batches of RB=2 ----
    #pragma unroll
    for (int b = 0; b < (ROWS / WAVES) / RB; ++b) {       // 2 batches
        const int rl0 = wave * (ROWS / WAVES) + b * RB;   // local row base
        const float* vb = v + (size_t)(row0 + rl0) * D_DIM;
        const float* xb = x + (size_t)(row0 + rl0) * D_DIM;

        float pp[RB][R_DIM];
        float xv[RB];
        #pragma unroll
        for (int k = 0; k < RB; ++k) {
            xv[k] = 0.0f;
            #pragma unroll
            for (int r = 0; r < R_DIM; ++r) pp[k][r] = 0.0f;
        }

        for (int i = 0; i < D_DIM / 256; ++i) {    // 8 iters, 256 floats/wave/iter
            const int d0 = i * 256 + lane * 4;
            float4 v4[RB], x4[RB];
            #pragma unroll
            for (int k = 0; k < RB; ++k) {
                v4[k] = *reinterpret_cast<const float4*>(vb + (size_t)k * D_DIM + d0);
                x4[k] = *reinterpret_cast<const float4*>(xb + (size_t)k * D_DIM + d0);
            }
            const float4 vw4 = *reinterpret_cast<const float4*>(vw_lds + d0);
            #pragma unroll
            for (int k = 0; k < RB; ++k) xv[k] += dot4(x4[k], vw4);
            #pragma unroll
            for (int r = 0; r < R_DIM; ++r) {
                const float4 u4 = *reinterpret_cast<const float4*>(u_lds + r * D_DIM + d0);
                #pragma unroll
                for (int k = 0; k < RB; ++k) pp[k][r] += dot4(v4[k], u4);
            }
        }

        // butterfly reduce across the 64-lane wave
        #pragma unroll
        for (int s = 32; s >= 1; s >>= 1) {
            #pragma unroll
            for (int k = 0; k < RB; ++k) {
                xv[k] += __shfl_xor(xv[k], s, 64);
                #pragma unroll
                for (int r = 0; r < R_DIM; ++r) pp[k][r] += __shfl_xor(pp[k][r], s, 64);
            }
        }
        if (lane == 0) {
            #pragma unroll
            for (int k = 0; k < RB; ++k) {
                const int rl = rl0 + k;
                if (row0 + rl < nrows) {
                    #pragma unroll
                    for (int r = 0; r < R_DIM; ++r)
                        sq_lds[rl * R_DIM + r] = pp[k][r] * pp[k][r];
                    fac_lds[rl] = 1.0f + 1.0f / (1.0f + __expf(-xv[k]));
                }
            }
        }
    }
    __syncthreads();

    // ---- phase 2: thread owns d = 2*tid, 2*tid+1; W in registers ----
    {
        const int dd = tid * 2;
        float w0[R_DIM], w1[R_DIM];
        const float4* p0 = reinterpret_cast<const float4*>(W + (size_t)dd * R_DIM);
        const float4* p1 = reinterpret_cast<const float4*>(W + (size_t)(dd + 1) * R_DIM);
        #pragma unroll
        for (int c = 0; c < 4; ++c) {
            *reinterpret_cast<float4*>(&w0[c * 4]) = p0[c];
            *reinterpret_cast<float4*>(&w1[c * 4]) = p1[c];
        }

        for (int rl = 0; rl < ROWS; ++rl) {
            if (row0 + rl >= nrows) break;
            float sqv[R_DIM];
            #pragma unroll
            for (int c = 0; c < 4; ++c)
                *reinterpret_cast<float4*>(&sqv[c * 4]) =
                    *reinterpret_cast<const float4*>(sq_lds + rl * R_DIM + c * 4);
            const float fac = fac_lds[rl];
            float o0 = 0.0f, o1 = 0.0f;
            #pragma unroll
            for (int r = 0; r < R_DIM; ++r) {
                o0 += sqv[r] * w0[r];
                o1 += sqv[r] * w1[r];
            }
            f32x2 o;
            o.x = clamp5(o0 * fac);
            o.y = clamp5(o1 * fac);
            __builtin_nontemporal_store(o,
                reinterpret_cast<f32x2*>(out + (size_t)(row0 + rl) * D_DIM + dd));
        }
    }
}

extern "C" void kernel_launch(void* const* d_in, const int* in_sizes, int n_in,
                              void* d_out, int out_size, void* d_ws, size_t ws_size,
                              hipStream_t stream) {
    const float* v  = (const float*)d_in[0];
    const float* x  = (const float*)d_in[1];
    const float* U  = (const float*)d_in[2];
    const float* W  = (const float*)d_in[3];
    const float* Vw = (const float*)d_in[4];
    float* out = (float*)d_out;

    const int nrows = in_sizes[0] / D_DIM;        // B*S = 16384
    const int grid  = (nrows + ROWS - 1) / ROWS;  // 256

    (void)hipFuncSetAttribute((const void*)lrc_kernel,
                              hipFuncAttributeMaxDynamicSharedMemorySize,
                              (int)SMEM_BYTES);
    lrc_kernel<<<grid, THREADS, SMEM_BYTES, stream>>>(v, x, U, W, Vw, out, nrows);
}